// Round 4
// baseline (1279.017 us; speedup 1.0000x reference)
//
#include <hip/hip_runtime.h>

// Problem constants (fixed by setup_inputs)
#define HQ 32
#define HKV 32
#define DH 128
#define HID 4096
#define BATCH 4
#define SEQ 1024
#define TOK (BATCH * SEQ)          // 4096
#define NQKV 12288                 // (HQ + 2*HKV) * DH
#define CACHE_ROWS 8192            // NUM_BLOCKS * BLOCK_SIZE
#define SM_SCALE 0.08838834764831845f  // 1/sqrt(128)

typedef unsigned short u16;
typedef __bf16 bf16x8 __attribute__((ext_vector_type(8)));
typedef float floatx4 __attribute__((ext_vector_type(4)));
typedef u16 u16x8 __attribute__((ext_vector_type(8)));
typedef u16 u16x4 __attribute__((ext_vector_type(4)));

__device__ __forceinline__ u16 f2bf(float x) {
  unsigned u = __float_as_uint(x);
  u += 0x7FFF + ((u >> 16) & 1);   // RNE
  return (u16)(u >> 16);
}
__device__ __forceinline__ float bf2f(u16 h) {
  return __uint_as_float(((unsigned)h) << 16);
}
// async global->LDS, 16B per lane. LDS dest is wave-uniform base + lane*16.
__device__ __forceinline__ void cp16(const void* g, void* l) {
  __builtin_amdgcn_global_load_lds(
      (__attribute__((address_space(1))) unsigned int*)(g),
      (__attribute__((address_space(3))) unsigned int*)(l), 16, 0, 0);
}

// ---------------- fp32 -> bf16 elementwise ----------------
__global__ void k_f32_to_bf16(const float4* __restrict__ x, ushort4* __restrict__ y) {
  int i = blockIdx.x * 256 + threadIdx.x;
  float4 v = x[i];
  ushort4 o;
  o.x = f2bf(v.x); o.y = f2bf(v.y); o.z = f2bf(v.z); o.w = f2bf(v.w);
  y[i] = o;
}

// ---------------- fp32 KxN -> bf16 NxK transpose ----------------
__global__ void k_transpose_bf16(const float* __restrict__ W, u16* __restrict__ Wt,
                                 int Kd, int Nd) {
  __shared__ float t[64][65];
  int n0 = blockIdx.x << 6, k0 = blockIdx.y << 6;
  int tx = threadIdx.x & 63, ty = threadIdx.x >> 6;
#pragma unroll
  for (int r = ty; r < 64; r += 4)
    t[r][tx] = W[(size_t)(k0 + r) * Nd + n0 + tx];
  __syncthreads();
  const int kg = threadIdx.x & 15, nr = threadIdx.x >> 4;
#pragma unroll
  for (int q = 0; q < 4; ++q) {
    int n = q * 16 + nr;
    u16x4 o;
#pragma unroll
    for (int j = 0; j < 4; ++j) o[j] = f2bf(t[kg * 4 + j][n]);
    *(u16x4*)&Wt[(size_t)(n0 + n) * Kd + k0 + kg * 4] = o;
  }
}

// ================= 256x256 8-phase bf16 GEMM =================
// K-loop identical to the verified R1-R3 schedule (do not touch).
// MODE 0: C = fp32 out. MODE 1: fused qkv epilogue (rope+scatter+vT), no C.
template <int Nd, int Kd, int MODE>
__global__ __launch_bounds__(512, 2) void k_gemm256(
    const u16* __restrict__ A, const u16* __restrict__ Bt, void* __restrict__ Cp,
    const float* __restrict__ cosp, const float* __restrict__ sinp,
    const int* __restrict__ slots, u16* __restrict__ qbp, u16* __restrict__ kbp,
    float* __restrict__ kcp, float* __restrict__ vcp, u16* __restrict__ vTp) {
  constexpr int GX = Nd / 256;
  constexpr int NWG = (TOK / 256) * GX;
  constexpr int BAND = 4 * GX;
  __shared__ __align__(16) u16 lds[2][2][256 * 64];  // [buf][0=A,1=B]

  const int bid = blockIdx.x;
  const int j = (bid & 7) * (NWG / 8) + (bid >> 3);  // XCD-chunked linear
  const int band = j / BAND, r = j % BAND;
  const int by = band * 4 + (r & 3), bx = r >> 2;
  const int bm = by << 8, bn = bx << 8;

  const int tid = threadIdx.x;
  const int wave = tid >> 6, lane = tid & 63;
  const int wm = wave >> 2, wn = wave & 3;
  const int quad = lane >> 4, l16 = lane & 15;

  auto stage_half = [&](const u16* src, int grow, int k0, u16* ldsb, int h) {
#pragma unroll
    for (int p = 0; p < 2; ++p) {
      int g = tid + (p << 9);
      int row = g >> 3, ps = g & 7;
      int ls = ps ^ (row & 7);
      cp16(src + (size_t)(grow + h * 128 + row) * Kd + k0 + ls * 8,
           ldsb + ((h * 128 + row) << 6) + (ps << 3));
    }
  };
  auto frag = [&](const u16* ldsb, int row, int slot) {
    return (const bf16x8*)(ldsb + (row << 6) + ((slot ^ (row & 7)) << 3));
  };

  const floatx4 FZ4 = {0.f, 0.f, 0.f, 0.f};
  floatx4 acc[8][4];
#pragma unroll
  for (int i = 0; i < 8; ++i)
#pragma unroll
    for (int j2 = 0; j2 < 4; ++j2) acc[i][j2] = FZ4;

  stage_half(A, bm, 0, &lds[0][0][0], 0);
  stage_half(A, bm, 0, &lds[0][0][0], 1);
  stage_half(Bt, bn, 0, &lds[0][1][0], 0);
  stage_half(Bt, bn, 0, &lds[0][1][0], 1);
  stage_half(Bt, bn, 64, &lds[1][1][0], 0);
  stage_half(Bt, bn, 64, &lds[1][1][0], 1);
  asm volatile("s_waitcnt vmcnt(4)" ::: "memory");
  asm volatile("s_barrier" ::: "memory");

  constexpr int NT = Kd / 64;
  for (int t = 0; t < NT; ++t) {
    const int c = t & 1, o = c ^ 1;
    const u16* cA = &lds[c][0][0];
    const u16* cB = &lds[c][1][0];
    const int k1 = (t + 1 < NT) ? (t + 1) * 64 : (Kd - 64);
    const int k2 = (t + 2 < NT) ? (t + 2) * 64 : (Kd - 64);

    bf16x8 bfr[4][2];
#pragma unroll
    for (int ph = 0; ph < 4; ++ph) {
      if (ph == 0) {
#pragma unroll
        for (int ni = 0; ni < 4; ++ni)
#pragma unroll
          for (int ks = 0; ks < 2; ++ks)
            bfr[ni][ks] = *frag(cB, wn * 64 + ni * 16 + l16, ks * 4 + quad);
      }
      bf16x8 af[2][2];
#pragma unroll
      for (int m = 0; m < 2; ++m)
#pragma unroll
        for (int ks = 0; ks < 2; ++ks)
          af[m][ks] = *frag(cA, wm * 128 + (ph * 2 + m) * 16 + l16, ks * 4 + quad);

      if (ph == 0) stage_half(A, bm, k1, &lds[o][0][0], 0);
      else if (ph == 1) stage_half(A, bm, k1, &lds[o][0][0], 1);
      else if (ph == 2) stage_half(Bt, bn, k2, &lds[c][1][0], 0);
      else stage_half(Bt, bn, k2, &lds[c][1][0], 1);

      asm volatile("s_barrier" ::: "memory");
      __builtin_amdgcn_s_setprio(1);
#pragma unroll
      for (int m = 0; m < 2; ++m)
#pragma unroll
        for (int ni = 0; ni < 4; ++ni)
#pragma unroll
          for (int ks = 0; ks < 2; ++ks)
            acc[ph * 2 + m][ni] = __builtin_amdgcn_mfma_f32_16x16x32_bf16(
                af[m][ks], bfr[ni][ks], acc[ph * 2 + m][ni], 0, 0, 0);
      __builtin_amdgcn_s_setprio(0);
      if (ph == 3) asm volatile("s_waitcnt vmcnt(4)" ::: "memory");
      asm volatile("s_barrier" ::: "memory");
    }
  }
  // drain all outstanding DMAs (incl. tail-clamped prefetch) in every wave,
  // then sync so LDS is safe to reuse / hand back.
  asm volatile("s_waitcnt vmcnt(0)" ::: "memory");
  __syncthreads();

  if (MODE == 0) {
    const int rbase = bm + wm * 128 + quad * 4;
    const int cbase = bn + wn * 64 + l16;
#pragma unroll
    for (int mi = 0; mi < 8; ++mi)
#pragma unroll
      for (int ni = 0; ni < 4; ++ni)
#pragma unroll
        for (int r2 = 0; r2 < 4; ++r2) {
          size_t idx = (size_t)(rbase + mi * 16 + r2) * Nd + (cbase + ni * 16);
          ((float*)Cp)[idx] = acc[mi][ni][r2];
        }
    return;
  }

  // ---- MODE 1: fused qkv epilogue ----
  // C-tile (256 tok x 256 ch, bf16) -> LDS, swizzled granules:
  // addr(row,col) = row*256 + (((col>>3) ^ swz(row))<<3) + (col&7), swz=(row^(row>>3))&7
  u16* Ct = (u16*)&lds[0][0][0];  // 128 KiB, exact fit
#pragma unroll
  for (int mi = 0; mi < 8; ++mi)
#pragma unroll
    for (int r2 = 0; r2 < 4; ++r2) {
      int row = wm * 128 + mi * 16 + quad * 4 + r2;
      int sw8 = (row ^ (row >> 3)) & 7;
#pragma unroll
      for (int ni = 0; ni < 4; ++ni) {
        int col = wn * 64 + ni * 16 + l16;
        Ct[row * 256 + (((col >> 3) ^ sw8) << 3) + (col & 7)] = f2bf(acc[mi][ni][r2]);
      }
    }
  const bool isV = (bn >= 2 * HQ * DH);
  if (isV) {
    // fp32 V cache straight from acc (unrounded), while LDS exchange settles
    const int chb = bn - 2 * HQ * DH + wn * 64 + l16;
#pragma unroll
    for (int mi = 0; mi < 8; ++mi)
#pragma unroll
      for (int r2 = 0; r2 < 4; ++r2) {
        int t = bm + wm * 128 + mi * 16 + quad * 4 + r2;
        int slot = slots[t];
#pragma unroll
        for (int ni = 0; ni < 4; ++ni)
          vcp[(size_t)slot * (HKV * DH) + chb + ni * 16] = acc[mi][ni][r2];
      }
  }
  __syncthreads();

  if (!isV) {
    const bool isQ = (bn < HQ * DH);
    const int hbase = isQ ? (bn >> 7) : ((bn - HQ * DH) >> 7);
#pragma unroll
    for (int it = 0; it < 8; ++it) {
      int u = tid + (it << 9);                 // 0..4095
      int tk = u >> 4, hh = (u >> 3) & 1, grp = u & 7;
      int t = bm + tk, bb = t >> 10, ss = t & 1023;
      int sw8 = (tk ^ (tk >> 3)) & 7;
      int c1 = hh * 128 + grp * 8;             // first-half col (i = grp*8..+7 < 64)
      u16x8 x1 = *(const u16x8*)&Ct[tk * 256 + (((c1 >> 3) ^ sw8) << 3)];
      u16x8 x2 = *(const u16x8*)&Ct[tk * 256 + ((((c1 + 64) >> 3) ^ sw8) << 3)];
      float4 c0 = *(const float4*)&cosp[t * 64 + grp * 8];
      float4 c4 = *(const float4*)&cosp[t * 64 + grp * 8 + 4];
      float4 s0 = *(const float4*)&sinp[t * 64 + grp * 8];
      float4 s4 = *(const float4*)&sinp[t * 64 + grp * 8 + 4];
      float cc[8] = {c0.x, c0.y, c0.z, c0.w, c4.x, c4.y, c4.z, c4.w};
      float sn[8] = {s0.x, s0.y, s0.z, s0.w, s4.x, s4.y, s4.z, s4.w};
      float f1[8], f2[8];
      u16x8 y1, y2;
#pragma unroll
      for (int jj = 0; jj < 8; ++jj) {
        float a = bf2f(x1[jj]), d = bf2f(x2[jj]);
        f1[jj] = a * cc[jj] - d * sn[jj];
        f2[jj] = d * cc[jj] + a * sn[jj];
      }
      if (isQ) {
#pragma unroll
        for (int jj = 0; jj < 8; ++jj) {
          y1[jj] = f2bf(f1[jj] * SM_SCALE);
          y2[jj] = f2bf(f2[jj] * SM_SCALE);
        }
        size_t oq = ((size_t)(bb * HQ + hbase + hh) * SEQ + ss) * DH + grp * 8;
        *(u16x8*)&qbp[oq] = y1;
        *(u16x8*)&qbp[oq + 64] = y2;
      } else {
#pragma unroll
        for (int jj = 0; jj < 8; ++jj) {
          y1[jj] = f2bf(f1[jj]);
          y2[jj] = f2bf(f2[jj]);
        }
        size_t ok = ((size_t)(bb * HKV + hbase + hh) * SEQ + ss) * DH + grp * 8;
        *(u16x8*)&kbp[ok] = y1;
        *(u16x8*)&kbp[ok + 64] = y2;
        int slot = slots[t];
        size_t oc = (size_t)slot * (HKV * DH) + (hbase + hh) * 128 + grp * 8;
        *(float4*)&kcp[oc] = make_float4(f1[0], f1[1], f1[2], f1[3]);
        *(float4*)&kcp[oc + 4] = make_float4(f1[4], f1[5], f1[6], f1[7]);
        *(float4*)&kcp[oc + 64] = make_float4(f2[0], f2[1], f2[2], f2[3]);
        *(float4*)&kcp[oc + 68] = make_float4(f2[4], f2[5], f2[6], f2[7]);
      }
    }
  } else {
    // vT (b,h,d,s) bf16 from LDS column reads
    const int hvb = (bn - 2 * HQ * DH) >> 7;
#pragma unroll
    for (int it = 0; it < 16; ++it) {
      int u = tid + (it << 9);                 // 0..8191
      int sgrp = u & 31, dd = (u >> 5) & 127, hh = u >> 12;
      int col = hh * 128 + dd, cg = col >> 3, ce = col & 7;
      u16x8 o;
#pragma unroll
      for (int jj = 0; jj < 8; ++jj) {
        int row = sgrp * 8 + jj;
        int sw8 = (row ^ (row >> 3)) & 7;
        o[jj] = Ct[row * 256 + ((cg ^ sw8) << 3) + ce];
      }
      int t0 = bm + sgrp * 8;
      int bb = t0 >> 10, ss = t0 & 1023;
      *(u16x8*)&vTp[((size_t)(bb * HKV + hvb + hh) * DH + dd) * SEQ + ss] = o;
    }
  }
}

// ---------------- flash attention (causal), QBLK=128 ----------------
// 8 waves x 16 q-rows; K/V dbuf in LDS, counted vmcnt(4); XOR-swizzled LDS.
// launch_bounds (512,2): cap 256 VGPR -> no scratch spill.
__global__ __launch_bounds__(512, 2) void k_attn(const u16* __restrict__ qb,
                                                 const u16* __restrict__ kb,
                                                 const u16* __restrict__ vT,
                                                 u16* __restrict__ attn) {
  __shared__ __align__(16) u16 lK[2][64 * 128];
  __shared__ __align__(16) u16 lV[2][128 * 64];
  __shared__ __align__(16) u16 lP[128 * 64];
  const int qt = blockIdx.x, h = blockIdx.y, b = blockIdx.z;
  const int bh = b * HQ + h;
  const int q0 = qt << 7;
  const int tid = threadIdx.x, wave = tid >> 6, lane = tid & 63;
  const int quad = lane >> 4, l16 = lane & 15;
  const u16* Qb = qb + (size_t)bh * SEQ * DH;
  const u16* Kb = kb + (size_t)bh * SEQ * DH;
  const u16* Vb = vT + (size_t)bh * DH * SEQ;

  bf16x8 qf[4];
#pragma unroll
  for (int ds = 0; ds < 4; ++ds)
    qf[ds] = *(const bf16x8*)&Qb[(size_t)(q0 + wave * 16 + l16) * DH + ds * 32 + quad * 8];

  const floatx4 FZ4 = {0.f, 0.f, 0.f, 0.f};
  floatx4 acc_o[8];
#pragma unroll
  for (int i = 0; i < 8; ++i) acc_o[i] = FZ4;
  float m_i[4] = {-1e30f, -1e30f, -1e30f, -1e30f};
  float l_i[4] = {0.f, 0.f, 0.f, 0.f};

  auto stageK = [&](int buf, int k0) {
#pragma unroll
    for (int p = 0; p < 2; ++p) {
      int g = tid + (p << 9);
      int row = g >> 4, gs = g & 15;
      int sl = gs ^ (row & 15);
      cp16(Kb + (size_t)(k0 + row) * DH + sl * 8, &lK[buf][g * 8]);
    }
  };
  auto stageV = [&](int buf, int k0) {
#pragma unroll
    for (int p = 0; p < 2; ++p) {
      int g = tid + (p << 9);
      int row = g >> 3, gs = g & 7;
      int sl = gs ^ (row & 7);
      cp16(Vb + (size_t)row * SEQ + k0 + sl * 8, &lV[buf][g * 8]);
    }
  };

  const int ktmax = 2 * qt + 1;
  stageK(0, 0);
  stageV(0, 0);
  for (int kt = 0; kt <= ktmax; ++kt) {
    const int cur = kt & 1;
    const int k0 = kt << 6;
    if (kt < ktmax) {
      stageK(cur ^ 1, k0 + 64);
      stageV(cur ^ 1, k0 + 64);
      asm volatile("s_waitcnt vmcnt(4)" ::: "memory");
    } else {
      asm volatile("s_waitcnt vmcnt(0)" ::: "memory");
    }
    __builtin_amdgcn_s_barrier();

    floatx4 accs[4];
    __builtin_amdgcn_s_setprio(1);
#pragma unroll
    for (int ni = 0; ni < 4; ++ni) {
      accs[ni] = FZ4;
      const int row = ni * 16 + l16;
#pragma unroll
      for (int ds = 0; ds < 4; ++ds) {
        bf16x8 kf = *(const bf16x8*)&lK[cur][row * 128 + (((ds * 4 + quad) ^ (row & 15)) << 3)];
        accs[ni] = __builtin_amdgcn_mfma_f32_16x16x32_bf16(qf[ds], kf, accs[ni], 0, 0, 0);
      }
    }
    __builtin_amdgcn_s_setprio(0);
    if (k0 + 63 > q0 + wave * 16) {
#pragma unroll
      for (int ni = 0; ni < 4; ++ni) {
        int ki = k0 + ni * 16 + l16;
#pragma unroll
        for (int r = 0; r < 4; ++r) {
          int qr = q0 + wave * 16 + quad * 4 + r;
          if (ki > qr) accs[ni][r] = -1e30f;
        }
      }
    }
    float mnew[4], alpha[4];
#pragma unroll
    for (int r = 0; r < 4; ++r) {
      float mx = fmaxf(fmaxf(accs[0][r], accs[1][r]), fmaxf(accs[2][r], accs[3][r]));
#pragma unroll
      for (int off = 1; off < 16; off <<= 1) mx = fmaxf(mx, __shfl_xor(mx, off));
      mnew[r] = fmaxf(m_i[r], mx);
      alpha[r] = __expf(m_i[r] - mnew[r]);
      m_i[r] = mnew[r];
    }
    float rs[4] = {0.f, 0.f, 0.f, 0.f};
#pragma unroll
    for (int ni = 0; ni < 4; ++ni)
#pragma unroll
      for (int r = 0; r < 4; ++r) {
        float p = __expf(accs[ni][r] - mnew[r]);
        rs[r] += p;
        int prow = wave * 16 + quad * 4 + r, pcol = ni * 16 + l16;
        lP[prow * 64 + ((((pcol >> 3) ^ (prow & 7))) << 3) + (pcol & 7)] = f2bf(p);
      }
#pragma unroll
    for (int r = 0; r < 4; ++r) {
      float sr = rs[r];
#pragma unroll
      for (int off = 1; off < 16; off <<= 1) sr += __shfl_xor(sr, off);
      l_i[r] = l_i[r] * alpha[r] + sr;
    }
#pragma unroll
    for (int dt = 0; dt < 8; ++dt)
#pragma unroll
      for (int r = 0; r < 4; ++r) acc_o[dt][r] *= alpha[r];

    bf16x8 pf[2];
    const int prow = wave * 16 + l16;
#pragma unroll
    for (int ks = 0; ks < 2; ++ks)
      pf[ks] = *(const bf16x8*)&lP[prow * 64 + (((ks * 4 + quad) ^ (prow & 7)) << 3)];
    __builtin_amdgcn_s_setprio(1);
#pragma unroll
    for (int dt = 0; dt < 8; ++dt) {
      const int vrow = dt * 16 + l16;
#pragma unroll
      for (int ks = 0; ks < 2; ++ks) {
        bf16x8 vf = *(const bf16x8*)&lV[cur][vrow * 64 + (((ks * 4 + quad) ^ (vrow & 7)) << 3)];
        acc_o[dt] = __builtin_amdgcn_mfma_f32_16x16x32_bf16(pf[ks], vf, acc_o[dt], 0, 0, 0);
      }
    }
    __builtin_amdgcn_s_setprio(0);
    asm volatile("s_waitcnt lgkmcnt(0)" ::: "memory");
    __builtin_amdgcn_s_barrier();
  }
  float inv[4];
#pragma unroll
  for (int r = 0; r < 4; ++r) inv[r] = 1.0f / l_i[r];
#pragma unroll
  for (int dt = 0; dt < 8; ++dt)
#pragma unroll
    for (int r = 0; r < 4; ++r) {
      int tok = b * SEQ + q0 + wave * 16 + quad * 4 + r;
      attn[(size_t)tok * HID + h * DH + dt * 16 + l16] = f2bf(acc_o[dt][r] * inv[r]);
    }
}

// ---------------- launcher ----------------
extern "C" void kernel_launch(void* const* d_in, const int* in_sizes, int n_in,
                              void* d_out, int out_size, void* d_ws, size_t ws_size,
                              hipStream_t stream) {
  (void)in_sizes; (void)n_in; (void)out_size; (void)ws_size;
  const float* hs = (const float*)d_in[0];
  const float* cosp = (const float*)d_in[1];
  const float* sinp = (const float*)d_in[2];
  const float* qkv_w = (const float*)d_in[3];
  const float* o_w = (const float*)d_in[4];
  const int* slots = (const int*)d_in[8];

  float* out = (float*)d_out;                          // (T, HID) fp32
  float* kc = out + (size_t)TOK * HID;                 // (8192, 32, 128) fp32
  float* vc = kc + (size_t)CACHE_ROWS * HKV * DH;

  // workspace (224 MiB):
  //  regA (96MB): W1t -> (after GEMM1) W2t
  //  regB (96MB): qb | kb | vT   (written by fused GEMM1 epilogue)
  //  regC (32MB): hs_bf16 -> attn
  u16* regA = (u16*)d_ws;
  u16* regB = regA + (size_t)NQKV * HID;
  u16* regC = regB + (size_t)NQKV * HID;
  u16* W1t = regA;
  u16* W2t = regA;
  u16* qb = regB;
  u16* kb = qb + (size_t)BATCH * HQ * SEQ * DH;
  u16* vTp = kb + (size_t)BATCH * HKV * SEQ * DH;
  u16* hsb = regC;
  u16* attnb = regC;

  // slots = arange(TOK) fully overwrites cache rows [0, TOK); zero only the rest
  const size_t halfRows = (size_t)(CACHE_ROWS - TOK) * HKV * DH;
  hipMemsetAsync(kc + (size_t)TOK * HKV * DH, 0, halfRows * sizeof(float), stream);
  hipMemsetAsync(vc + (size_t)TOK * HKV * DH, 0, halfRows * sizeof(float), stream);

  k_f32_to_bf16<<<TOK * HID / 1024, 256, 0, stream>>>((const float4*)hs, (ushort4*)hsb);
  k_transpose_bf16<<<dim3(NQKV / 64, HID / 64), 256, 0, stream>>>(qkv_w, W1t, HID, NQKV);
  k_gemm256<NQKV, HID, 1><<<(TOK / 256) * (NQKV / 256), 512, 0, stream>>>(
      hsb, W1t, nullptr, cosp, sinp, slots, qb, kb, kc, vc, vTp);
  k_transpose_bf16<<<dim3(HID / 64, HID / 64), 256, 0, stream>>>(o_w, W2t, HID, HID);
  k_attn<<<dim3(SEQ / 128, HQ, BATCH), 512, 0, stream>>>(qb, kb, vTp, attnb);
  k_gemm256<HID, HID, 0><<<(TOK / 256) * (HID / 256), 512, 0, stream>>>(
      attnb, W2t, out, nullptr, nullptr, nullptr, nullptr, nullptr, nullptr, nullptr,
      nullptr);
}